// Round 7
// baseline (168.812 us; speedup 1.0000x reference)
//
#include <hip/hip_runtime.h>
#include <hip/hip_bf16.h>

#define NROWS 131072
#define KEXP 16
#define MPC 128
#define DIMD 64

typedef float f32x4  __attribute__((ext_vector_type(4)));
typedef short s16x8  __attribute__((ext_vector_type(8)));

#define L2E 1.4426950408889634f
#define LN2 0.6931471805599453f
#define ABIAS_OFF 262144   // byte offset of bias region inside abff (A region = 256 KB)

static __device__ inline unsigned int b2u(__hip_bfloat162 h) {
    union { __hip_bfloat162 h; unsigned int u; } c;
    c.h = h;
    return c.u;
}

static __device__ inline int4 cvt8s(float4 f0, float4 f1, float sc) {
    __hip_bfloat162 p0 = __float22bfloat162_rn(make_float2(f0.x * sc, f0.y * sc));
    __hip_bfloat162 p1 = __float22bfloat162_rn(make_float2(f0.z * sc, f0.w * sc));
    __hip_bfloat162 p2 = __float22bfloat162_rn(make_float2(f1.x * sc, f1.y * sc));
    __hip_bfloat162 p3 = __float22bfloat162_rn(make_float2(f1.z * sc, f1.w * sc));
    int4 pk;
    pk.x = (int)b2u(p0); pk.y = (int)b2u(p1); pk.z = (int)b2u(p2); pk.w = (int)b2u(p3);
    return pk;
}

// async 16B/lane global->LDS DMA (wave-uniform LDS base + lane*16)
static __device__ inline void async_copy16(const void* g, void* l) {
    __builtin_amdgcn_global_load_lds(
        (const __attribute__((address_space(1))) unsigned int*)g,
        (__attribute__((address_space(3))) unsigned int*)l, 16, 0, 0);
}

// abff layout (16x16x32 fragments):
//  A region (256 KB): per expert k, 16 chunks c = mt*2+kc (mt 0..7, kc 0..1) of
//    1 KB; lane ul holds 8 bf16: a[k][mt*16 + (ul&15)][kc*32 + (ul>>4)*8 + j]*L2E
//  bias region (32 KB @ ABIAS_OFF): per (k, half h) one 1 KB slot; first 64 f32 =
//    b[k][h*64 + i]*L2E (rest of slot padding so the DMA can copy a uniform 1 KB)
// Also zeroes out[] (replaces hipMemsetAsync).
__global__ void prep_kernel(const float* __restrict__ a, const float* __restrict__ b,
                            short* __restrict__ abff, float* __restrict__ out) {
    const int u = blockIdx.x * 256 + threadIdx.x;   // grid 72*256 = 18432
    if (u < 16384) {
        const int k  = u >> 10;
        const int c  = (u >> 6) & 15;
        const int ul = u & 63;
        const int mt = c >> 1;
        const int kc = c & 1;
        const float* p = a + (size_t)(k * MPC + mt * 16 + (ul & 15)) * DIMD
                           + kc * 32 + (ul >> 4) * 8;
        int4 pk = cvt8s(*(const float4*)(p), *(const float4*)(p + 4), L2E);
        *(int4*)(abff + (size_t)u * 8) = pk;
    } else if (u < 16384 + 2048) {
        const int v = u - 16384;
        const int k = v >> 7;
        const int m = v & 127;
        float* bf = (float*)((char*)abff + ABIAS_OFF);
        bf[(size_t)(k * 2 + (m >> 6)) * 256 + (m & 63)] = b[k * MPC + m] * L2E;
    }
    for (int i = u; i < NROWS; i += 72 * 256) out[i] = 0.f;
}

// Round-7: 16x16x32 MFMA restructure to reach HONEST 8 waves/SIMD.
// Diagnosis: rounds 0/4/6 all ~55-57us with per-SIMD pipes <30% busy and
// ~3 waves/SIMD -> resident-wave-starved (latency-bound). Occupancy step is
// binary at 64 total regs (m69); the 32x32x16 structure needs ~68 (rounds 3/5
// spilled when forced). 16x16x32 shrinks acc 16->8 regs (f32x4 x2) and kills
// the bias MFMA: acc is INITIALIZED from a 4-float ds_read of bias (C row =
// (l>>4)*4+reg depends only on m). Estimated total ~52-60 regs -> force
// __launch_bounds__(256,8). LDS 2 x 9 KB = 18 KB -> 8 blocks/CU -> 32 waves/CU.
// Spill canary: WRITE_SIZE must stay ~1 MB.
__global__ __launch_bounds__(256, 8)
void fused_kernel(const float* __restrict__ x, const float* __restrict__ s,
                  const short* __restrict__ abff, float* __restrict__ out) {
    __shared__ int4 abuf[2][576];   // 2 x 9 KB: A chunks 0..7 @ ch*1024, bias @ 8192

    const int tid  = threadIdx.x;
    const int w    = tid >> 6;
    const int l    = tid & 63;

    const int family = blockIdx.x & 1;
    const int r0w    = (blockIdx.x >> 1) * 128 + w * 32;   // wave owns rows r0w..r0w+31

    // persistent x B-fragments: Bf[rt][kc] = x[r0w + rt*16 + (l&15)][kc*32 + (l>>4)*8 ..+7]
    union { int4 i; s16x8 v; } Bf[2][2];
#pragma unroll
    for (int rt = 0; rt < 2; ++rt)
#pragma unroll
        for (int kc = 0; kc < 2; ++kc) {
            const float* gp = x + (size_t)(r0w + rt * 16 + (l & 15)) * DIMD
                                + kc * 32 + (l >> 4) * 8;
            float4 f0 = *(const float4*)(gp);
            float4 f1 = *(const float4*)(gp + 4);
            Bf[rt][kc].i = cvt8s(f0, f1, 1.0f);
        }

    const int kf0 = family * 8;
    const char* ab = (const char*)abff;

    // initial DMA: expert kf0 half 0 -> abuf[0] (8 A chunks + 1 bias chunk)
#pragma unroll
    for (int i = 0; i < 3; ++i) {
        const int ch = w + 4 * i;
        if (ch < 8)
            async_copy16(ab + (size_t)kf0 * 16384 + ch * 1024 + l * 16,
                         (char*)&abuf[0][0] + ch * 1024);
        else if (ch == 8)
            async_copy16(ab + ABIAS_OFF + (size_t)kf0 * 2048 + l * 16,
                         (char*)&abuf[0][0] + 8192);
    }
    __syncthreads();   // barrier drains DMA (vmcnt0 before s_barrier)

    float racc0 = 0.f, racc1 = 0.f;

#define COMPUTE(B)                                                                  \
    do {                                                                            \
        const char* Ab = (const char*)&abuf[B][0];                                  \
        _Pragma("unroll")                                                           \
        for (int mtl = 0; mtl < 4; ++mtl) {                                         \
            f32x4 bv = *(const f32x4*)(Ab + 8192 + mtl * 64 + ((l >> 4) << 4));     \
            f32x4 acc0 = bv, acc1 = bv;                                             \
            s16x8 Af0 = *(const s16x8*)(Ab + (mtl * 2 + 0) * 1024 + l * 16);        \
            acc0 = __builtin_amdgcn_mfma_f32_16x16x32_bf16(Af0, Bf[0][0].v, acc0, 0, 0, 0); \
            acc1 = __builtin_amdgcn_mfma_f32_16x16x32_bf16(Af0, Bf[1][0].v, acc1, 0, 0, 0); \
            s16x8 Af1 = *(const s16x8*)(Ab + (mtl * 2 + 1) * 1024 + l * 16);        \
            acc0 = __builtin_amdgcn_mfma_f32_16x16x32_bf16(Af1, Bf[0][1].v, acc0, 0, 0, 0); \
            acc1 = __builtin_amdgcn_mfma_f32_16x16x32_bf16(Af1, Bf[1][1].v, acc1, 0, 0, 0); \
            e0a += __builtin_amdgcn_exp2f(acc0[0]);                                 \
            e0b += __builtin_amdgcn_exp2f(acc0[1]);                                 \
            e0a += __builtin_amdgcn_exp2f(acc0[2]);                                 \
            e0b += __builtin_amdgcn_exp2f(acc0[3]);                                 \
            e1a += __builtin_amdgcn_exp2f(acc1[0]);                                 \
            e1b += __builtin_amdgcn_exp2f(acc1[1]);                                 \
            e1a += __builtin_amdgcn_exp2f(acc1[2]);                                 \
            e1b += __builtin_amdgcn_exp2f(acc1[3]);                                 \
        }                                                                           \
    } while (0)

    for (int k = 0; k < 8; ++k) {   // runtime loop: small code, small regs
        const int kf  = kf0 + k;
        const float sk2 = s[kf] * LN2;
        float e0a = 0.f, e0b = 0.f, e1a = 0.f, e1b = 0.f;

        // ---- half-stage 0: prefetch half 1 -> abuf[1]; compute abuf[0]
#pragma unroll
        for (int i = 0; i < 3; ++i) {
            const int ch = w + 4 * i;
            if (ch < 8)
                async_copy16(ab + (size_t)kf * 16384 + 8192 + ch * 1024 + l * 16,
                             (char*)&abuf[1][0] + ch * 1024);
            else if (ch == 8)
                async_copy16(ab + ABIAS_OFF + (size_t)kf * 2048 + 1024 + l * 16,
                             (char*)&abuf[1][0] + 8192);
        }
        COMPUTE(0);
        __syncthreads();   // abuf[0] free; abuf[1] drained

        // ---- half-stage 1: prefetch next expert half 0 -> abuf[0]; compute abuf[1]
        if (k < 7) {
#pragma unroll
            for (int i = 0; i < 3; ++i) {
                const int ch = w + 4 * i;
                if (ch < 8)
                    async_copy16(ab + (size_t)(kf + 1) * 16384 + ch * 1024 + l * 16,
                                 (char*)&abuf[0][0] + ch * 1024);
                else if (ch == 8)
                    async_copy16(ab + ABIAS_OFF + (size_t)(kf + 1) * 2048 + l * 16,
                                 (char*)&abuf[0][0] + 8192);
            }
        }
        COMPUTE(1);

        // per-expert reduce: sum over lanes {l, l^16, l^32, l^48} (same n, other m)
        float tot0 = e0a + e0b;
        tot0 += __shfl_xor(tot0, 16);
        tot0 += __shfl_xor(tot0, 32);
        float tot1 = e1a + e1b;
        tot1 += __shfl_xor(tot1, 16);
        tot1 += __shfl_xor(tot1, 32);
        racc0 = fmaf(sk2, __log2f(tot0), racc0);
        racc1 = fmaf(sk2, __log2f(tot1), racc1);

        __syncthreads();   // abuf[1] free; abuf[0] (next expert) drained
    }
#undef COMPUTE

    // lane l<16 holds rows r0w+0..15 (rt0), lanes 16..31 rows r0w+16..31 (rt1)
    if (l < 32)
        atomicAdd(&out[r0w + l], (l < 16) ? racc0 : racc1);
}

extern "C" void kernel_launch(void* const* d_in, const int* in_sizes, int n_in,
                              void* d_out, int out_size, void* d_ws, size_t ws_size,
                              hipStream_t stream) {
    const float* x = (const float*)d_in[0];
    const float* s = (const float*)d_in[1];
    const float* a = (const float*)d_in[2];
    const float* b = (const float*)d_in[3];
    float* out = (float*)d_out;

    short* abff = (short*)d_ws;   // A 256 KB + bias 32 KB = 288 KB

    prep_kernel<<<72, 256, 0, stream>>>(a, b, abff, out);
    fused_kernel<<<NROWS / 64, 256, 0, stream>>>(x, s, abff, out);
}